// Round 3
// baseline (58.504 us; speedup 1.0000x reference)
//
#include <hip/hip_runtime.h>
#include <math.h>

// ContrastiveLoss via 1-D histogram approximation (512 mean-centered bins).
// reps = concat(emb_i, emb_j) (N = 2B fp32 scalars)
// denom_a ~= sum_k n_k * f(r_a - m_k) - e^2,  f(x) = exp2(C*rcp(1+|x|))
// loss = (1/N) * sum_a [ log(denom_a) - 2*sim(a, pair(a)) ]   (positives exact)
//
// K1: single-block concat + LDS histogram (no zero kernel, no global atomics)
// K2: 2048 blocks x 256, 8 rows/block, per-block partial -> plain store
// K3: single-block reduce of 2048 partials -> out[0]
// No same-address global atomics anywhere (round-2's hidden ~25us tail).

#define BLOCK 256
#define ROWS_PER_BLOCK 8
#define NBINS 512
#define CHUNK (NBINS / BLOCK)      // 2 bins per thread in K2
#define RLO -6.0f
#define RHI 6.0f
#define INVW ((float)NBINS / (RHI - RLO))
// (1/TEMP) * log2(e), TEMP = 0.5
#define C_EXP2 (2.0f * 1.4426950408889634f)
#define SELF_TERM 7.3890560989306495f   // e^2, the b==a term to remove

__global__ __launch_bounds__(1024)
void hist_kernel(const float* __restrict__ emb_i,
                 const float* __restrict__ emb_j,
                 float* __restrict__ reps,
                 float2* __restrict__ hist_g, int B) {
    __shared__ float hn[NBINS];
    __shared__ float hs[NBINS];
    const int t = threadIdx.x;
    for (int k = t; k < NBINS; k += 1024) { hn[k] = 0.0f; hs[k] = 0.0f; }
    __syncthreads();
    for (int i = t; i < B; i += 1024) {
        float vi = emb_i[i];
        float vj = emb_j[i];
        reps[i] = vi;
        reps[i + B] = vj;
        int ki = min(max((int)((vi - RLO) * INVW), 0), NBINS - 1);
        atomicAdd(&hn[ki], 1.0f);
        atomicAdd(&hs[ki], vi);
        int kj = min(max((int)((vj - RLO) * INVW), 0), NBINS - 1);
        atomicAdd(&hn[kj], 1.0f);
        atomicAdd(&hs[kj], vj);
    }
    __syncthreads();
    for (int k = t; k < NBINS; k += 1024)
        hist_g[k] = make_float2(hn[k], hs[k]);
}

__global__ __launch_bounds__(BLOCK)
void denom_kernel(const float* __restrict__ reps,
                  const float2* __restrict__ hist_g,
                  float* __restrict__ partials, int B) {
    const int N = 2 * B;
    const int row0 = blockIdx.x * ROWS_PER_BLOCK;
    const int t = threadIdx.x;

    float ra[ROWS_PER_BLOCK];
#pragma unroll
    for (int r = 0; r < ROWS_PER_BLOCK; ++r)
        ra[r] = reps[row0 + r];

    // This thread's bins; sum -> mean in registers.
    float nn[CHUNK], mm[CHUNK];
#pragma unroll
    for (int j = 0; j < CHUNK; ++j) {
        float2 h = hist_g[j * BLOCK + t];
        nn[j] = h.x;
        mm[j] = (h.x > 0.0f) ? h.y * __builtin_amdgcn_rcpf(h.x) : 0.0f;
    }

    float acc[ROWS_PER_BLOCK];
#pragma unroll
    for (int r = 0; r < ROWS_PER_BLOCK; ++r) acc[r] = 0.0f;

#pragma unroll
    for (int r = 0; r < ROWS_PER_BLOCK; ++r) {
#pragma unroll
        for (int j = 0; j < CHUNK; ++j) {
            float d = fabsf(ra[r] - mm[j]);
            float s = __builtin_amdgcn_rcpf(1.0f + d);
            acc[r] += nn[j] * __builtin_amdgcn_exp2f(C_EXP2 * s);
        }
    }

    // Per-row block reduction: wave shuffle then LDS across the 4 waves.
    __shared__ float red[BLOCK / 64][ROWS_PER_BLOCK];
    __shared__ float rowv[ROWS_PER_BLOCK];
#pragma unroll
    for (int r = 0; r < ROWS_PER_BLOCK; ++r) {
        float v = acc[r];
        for (int off = 32; off > 0; off >>= 1)
            v += __shfl_down(v, off, 64);
        if ((t & 63) == 0) red[t >> 6][r] = v;
    }
    __syncthreads();

    if (t < ROWS_PER_BLOCK) {
        float denom = 0.0f;
#pragma unroll
        for (int w = 0; w < BLOCK / 64; ++w) denom += red[w][t];
        denom -= SELF_TERM;   // remove b==a contribution

        int a = row0 + t;
        int p = a + B;
        if (p >= N) p -= N;
        float pos = __builtin_amdgcn_rcpf(1.0f + fabsf(reps[p] - reps[a]));
        rowv[t] = __logf(denom) - 2.0f * pos;
    }
    __syncthreads();

    if (t == 0) {
        float s = 0.0f;
#pragma unroll
        for (int r = 0; r < ROWS_PER_BLOCK; ++r) s += rowv[r];
        partials[blockIdx.x] = s;   // plain store, no atomic
    }
}

__global__ __launch_bounds__(BLOCK)
void loss_kernel(const float* __restrict__ partials,
                 float* __restrict__ out, int nparts, int N) {
    float acc = 0.0f;
    for (int i = threadIdx.x; i < nparts; i += BLOCK)
        acc += partials[i];
    for (int off = 32; off > 0; off >>= 1)
        acc += __shfl_down(acc, off, 64);
    __shared__ float red[BLOCK / 64];
    if ((threadIdx.x & 63) == 0) red[threadIdx.x >> 6] = acc;
    __syncthreads();
    if (threadIdx.x == 0) {
        float s = 0.0f;
#pragma unroll
        for (int w = 0; w < BLOCK / 64; ++w) s += red[w];
        out[0] = s / (float)N;
    }
}

extern "C" void kernel_launch(void* const* d_in, const int* in_sizes, int n_in,
                              void* d_out, int out_size, void* d_ws, size_t ws_size,
                              hipStream_t stream) {
    const float* emb_i = (const float*)d_in[0];
    const float* emb_j = (const float*)d_in[1];
    const int B = in_sizes[0];
    const int N = 2 * B;
    const int nparts = N / ROWS_PER_BLOCK;

    float*  reps     = (float*)d_ws;               // N floats
    float2* hist     = (float2*)(reps + N);        // NBINS float2
    float*  partials = (float*)(hist + NBINS);     // nparts floats
    float*  out      = (float*)d_out;

    hist_kernel<<<1, 1024, 0, stream>>>(emb_i, emb_j, reps, hist, B);
    denom_kernel<<<nparts, BLOCK, 0, stream>>>(reps, hist, partials, B);
    loss_kernel<<<1, BLOCK, 0, stream>>>(partials, out, nparts, N);
}

// Round 4
// 55.435 us; speedup vs baseline: 1.0554x; 1.0554x over previous
//
#include <hip/hip_runtime.h>
#include <math.h>

// ContrastiveLoss via 1-D histogram approximation (512 mean-centered bins).
// reps = concat(emb_i, emb_j) (N = 2B fp32 scalars)
// denom_a ~= sum_k n_k * f(r_a - m_k) - e^2,  f(x) = exp2(C*rcp(1+|x|))
// loss = (1/N) * sum_a [ log(denom_a) - 2*sim(a, pair(a)) ]   (positives exact)
//
// Round-4 structure (2 launches):
//  K1 (1 block): concat + LDS histogram with NATIVE INT atomics (round-3's
//     44us was the float-atomicAdd CAS loop), float4 loads; resets ticket.
//  K2 (2048 blocks): denom evals (8.4M rcp+exp2), per-block partial store,
//     last-block (ticket) reduces partials -> out[0]. No float global atomics.

#define BLOCK 256
#define ROWS_PER_BLOCK 8
#define NBINS 512
#define CHUNK (NBINS / BLOCK)      // 2 bins per thread in K2
#define RLO -6.0f
#define RHI 6.0f
#define INVW ((float)NBINS / (RHI - RLO))
#define SCALE 16384.0f
#define INV_SCALE (1.0f / 16384.0f)
// (1/TEMP) * log2(e), TEMP = 0.5
#define C_EXP2 (2.0f * 1.4426950408889634f)
#define SELF_TERM 7.3890560989306495f   // e^2, the b==a term to remove

__device__ __forceinline__ void bin_one(float v, int* hn, int* hs) {
    int k = (int)((v - RLO) * INVW);
    k = min(max(k, 0), NBINS - 1);
    atomicAdd(&hn[k], 1);                       // native ds_add_u32
    atomicAdd(&hs[k], (int)rintf(v * SCALE));   // fixed-point value sum
}

__global__ __launch_bounds__(1024)
void hist_kernel(const float4* __restrict__ emb_i4,
                 const float4* __restrict__ emb_j4,
                 float4* __restrict__ reps4,
                 int2* __restrict__ hist_g,
                 int* __restrict__ ticket, int B4) {
    __shared__ int hn[NBINS];
    __shared__ int hs[NBINS];
    const int t = threadIdx.x;
    for (int k = t; k < NBINS; k += 1024) { hn[k] = 0; hs[k] = 0; }
    if (t == 0) *ticket = 0;   // reset for K2's last-block pattern (every call)
    __syncthreads();

    for (int i = t; i < B4; i += 1024) {   // B4 = B/4 = 2048 -> 2 iters
        float4 vi = emb_i4[i];
        float4 vj = emb_j4[i];
        reps4[i] = vi;
        reps4[i + B4] = vj;
        bin_one(vi.x, hn, hs); bin_one(vi.y, hn, hs);
        bin_one(vi.z, hn, hs); bin_one(vi.w, hn, hs);
        bin_one(vj.x, hn, hs); bin_one(vj.y, hn, hs);
        bin_one(vj.z, hn, hs); bin_one(vj.w, hn, hs);
    }
    __syncthreads();
    for (int k = t; k < NBINS; k += 1024)
        hist_g[k] = make_int2(hn[k], hs[k]);
}

__global__ __launch_bounds__(BLOCK)
void denom_kernel(const float* __restrict__ reps,
                  const int2* __restrict__ hist_g,
                  float* __restrict__ partials,
                  int* __restrict__ ticket,
                  float* __restrict__ out, int B) {
    const int N = 2 * B;
    const int row0 = blockIdx.x * ROWS_PER_BLOCK;
    const int t = threadIdx.x;
    const int nblocks = gridDim.x;

    float ra[ROWS_PER_BLOCK];
#pragma unroll
    for (int r = 0; r < ROWS_PER_BLOCK; ++r)
        ra[r] = reps[row0 + r];

    // This thread's bins; int (count, fixed-point sum) -> (n, mean).
    float nn[CHUNK], mm[CHUNK];
#pragma unroll
    for (int j = 0; j < CHUNK; ++j) {
        int2 h = hist_g[j * BLOCK + t];
        float n = (float)h.x;
        nn[j] = n;
        mm[j] = (h.x > 0)
                  ? ((float)h.y * INV_SCALE) * __builtin_amdgcn_rcpf(n)
                  : 0.0f;
    }

    float acc[ROWS_PER_BLOCK];
#pragma unroll
    for (int r = 0; r < ROWS_PER_BLOCK; ++r) acc[r] = 0.0f;

#pragma unroll
    for (int r = 0; r < ROWS_PER_BLOCK; ++r) {
#pragma unroll
        for (int j = 0; j < CHUNK; ++j) {
            float d = fabsf(ra[r] - mm[j]);
            float s = __builtin_amdgcn_rcpf(1.0f + d);
            acc[r] += nn[j] * __builtin_amdgcn_exp2f(C_EXP2 * s);
        }
    }

    // Per-row block reduction: wave shuffle then LDS across the 4 waves.
    __shared__ float red[BLOCK / 64][ROWS_PER_BLOCK];
    __shared__ float rowv[ROWS_PER_BLOCK];
#pragma unroll
    for (int r = 0; r < ROWS_PER_BLOCK; ++r) {
        float v = acc[r];
        for (int off = 32; off > 0; off >>= 1)
            v += __shfl_down(v, off, 64);
        if ((t & 63) == 0) red[t >> 6][r] = v;
    }
    __syncthreads();

    if (t < ROWS_PER_BLOCK) {
        float denom = 0.0f;
#pragma unroll
        for (int w = 0; w < BLOCK / 64; ++w) denom += red[w][t];
        denom -= SELF_TERM;   // remove b==a contribution

        int a = row0 + t;
        int p = a + B;
        if (p >= N) p -= N;
        float pos = __builtin_amdgcn_rcpf(1.0f + fabsf(reps[p] - reps[a]));
        rowv[t] = __logf(denom) - 2.0f * pos;
    }
    __syncthreads();

    __shared__ int amLast;
    if (t == 0) {
        float s = 0.0f;
#pragma unroll
        for (int r = 0; r < ROWS_PER_BLOCK; ++r) s += rowv[r];
        partials[blockIdx.x] = s;        // plain store
        __threadfence();                 // make partial visible device-wide
        int old = atomicAdd(ticket, 1);  // native int atomic
        amLast = (old == nblocks - 1) ? 1 : 0;
    }
    __syncthreads();

    if (amLast) {
        __threadfence();   // acquire: see all partials
        float acc2 = 0.0f;
        for (int i = t; i < nblocks; i += BLOCK)
            acc2 += partials[i];
        for (int off = 32; off > 0; off >>= 1)
            acc2 += __shfl_down(acc2, off, 64);
        __shared__ float red2[BLOCK / 64];
        if ((t & 63) == 0) red2[t >> 6] = acc2;
        __syncthreads();
        if (t == 0) {
            float s = 0.0f;
#pragma unroll
            for (int w = 0; w < BLOCK / 64; ++w) s += red2[w];
            out[0] = s / (float)N;
        }
    }
}

extern "C" void kernel_launch(void* const* d_in, const int* in_sizes, int n_in,
                              void* d_out, int out_size, void* d_ws, size_t ws_size,
                              hipStream_t stream) {
    const float* emb_i = (const float*)d_in[0];
    const float* emb_j = (const float*)d_in[1];
    const int B = in_sizes[0];
    const int N = 2 * B;
    const int nblocks = N / ROWS_PER_BLOCK;   // 2048

    float* reps     = (float*)d_ws;                  // N floats (64 KB)
    int2*  hist     = (int2*)(reps + N);             // NBINS int2 (4 KB)
    float* partials = (float*)(hist + NBINS);        // nblocks floats (8 KB)
    int*   ticket   = (int*)(partials + nblocks);    // 1 int
    float* out      = (float*)d_out;

    hist_kernel<<<1, 1024, 0, stream>>>((const float4*)emb_i,
                                        (const float4*)emb_j,
                                        (float4*)reps, hist, ticket, B / 4);
    denom_kernel<<<nblocks, BLOCK, 0, stream>>>(reps, hist, partials,
                                                ticket, out, B);
}

// Round 5
// 18.427 us; speedup vs baseline: 3.1750x; 3.0084x over previous
//
#include <hip/hip_runtime.h>
#include <math.h>

// ContrastiveLoss via per-block-replicated 1-D histogram (512 mean-centered
// bins). reps = concat(emb_i, emb_j) conceptually; never materialized.
// denom_a ~= sum_k n_k * f(r_a - m_k) - e^2,  f(x) = exp2(C*rcp(1+|x|))
// loss = (1/N) * sum_a [ log(denom_a) - 2*sim(a, pair(a)) ]   (positives exact)
//
// Round-5: round-4's 47us was the 2048 same-address device-scope atomics +
// per-block threadfence (L2 writeback on 8 non-coherent XCDs). Fix: NO
// cross-block communication at all.
//  K_a (64 blocks x 1024): each block builds its OWN LDS histogram of all N
//      values (int LDS atomics, ~2-4us, fully parallel across blocks), then
//      denoms for its 256 rows (4 threads/row, wave-uniform bin quarters ->
//      broadcast ds_reads), block-reduce -> ONE plain partial store.
//  K_b (1 block x 64): reduce 64 partials -> out[0].

#define NBINS 512
#define RLO -6.0f
#define RHI 6.0f
#define INVW ((float)NBINS / (RHI - RLO))
#define SCALE 16384.0f
#define INV_SCALE (1.0f / 16384.0f)
// (1/TEMP) * log2(e), TEMP = 0.5
#define C_EXP2 (2.0f * 1.4426950408889634f)
#define SELF_TERM 7.3890560989306495f   // e^2, the b==a term to remove
#define ROWS_PER_BLOCK 256
#define KA_THREADS 1024
#define QUARTERS 4
#define BINS_PER_Q (NBINS / QUARTERS)   // 128

__device__ __forceinline__ void bin_one(float v, int* hn, int* hs) {
    int k = (int)((v - RLO) * INVW);
    k = min(max(k, 0), NBINS - 1);
    atomicAdd(&hn[k], 1);                       // native ds_add_u32
    atomicAdd(&hs[k], (int)rintf(v * SCALE));   // fixed-point value sum
}

__global__ __launch_bounds__(KA_THREADS)
void denom_kernel(const float4* __restrict__ emb_i4,
                  const float4* __restrict__ emb_j4,
                  const float* __restrict__ emb_i,
                  const float* __restrict__ emb_j,
                  float* __restrict__ partials, int B) {
    __shared__ int hn[NBINS];
    __shared__ int hs[NBINS];
    __shared__ float2 hist_f[NBINS];
    __shared__ float part[QUARTERS][ROWS_PER_BLOCK];
    __shared__ float red[KA_THREADS / 64];

    const int t = threadIdx.x;
    const int B4 = B / 4;

    // ---- per-block histogram of ALL N = 2B values (LDS only) ----
    if (t < NBINS) { hn[t] = 0; hs[t] = 0; }
    __syncthreads();
    for (int i = t; i < B4; i += KA_THREADS) {   // B4 = 2048 -> 2 iters
        float4 vi = emb_i4[i];
        float4 vj = emb_j4[i];
        bin_one(vi.x, hn, hs); bin_one(vi.y, hn, hs);
        bin_one(vi.z, hn, hs); bin_one(vi.w, hn, hs);
        bin_one(vj.x, hn, hs); bin_one(vj.y, hn, hs);
        bin_one(vj.z, hn, hs); bin_one(vj.w, hn, hs);
    }
    __syncthreads();
    if (t < NBINS) {
        float n = (float)hn[t];
        float m = (hn[t] > 0)
                    ? ((float)hs[t] * INV_SCALE) * __builtin_amdgcn_rcpf(n)
                    : 0.0f;
        hist_f[t] = make_float2(n, m);
    }
    __syncthreads();

    // ---- denom: 4 threads per row; q uniform per wave -> broadcast reads ---
    const int q   = t >> 8;          // 0..3, wave-uniform
    const int row = t & 255;
    const int a   = blockIdx.x * ROWS_PER_BLOCK + row;
    const float ra = (a < B) ? emb_i[a] : emb_j[a - B];

    float acc = 0.0f;
#pragma unroll
    for (int j = 0; j < BINS_PER_Q; ++j) {
        float2 h = hist_f[q * BINS_PER_Q + j];   // same addr across wave
        float d = fabsf(ra - h.y);
        float s = __builtin_amdgcn_rcpf(1.0f + d);
        acc += h.x * __builtin_amdgcn_exp2f(C_EXP2 * s);
    }
    part[q][row] = acc;              // stride-1 across lanes: conflict-free
    __syncthreads();

    // ---- per-row finalize + block reduce (threads 0..255) ----
    float rowv = 0.0f;
    if (t < ROWS_PER_BLOCK) {
        float denom = part[0][t] + part[1][t] + part[2][t] + part[3][t]
                      - SELF_TERM;
        float pv = (a < B) ? emb_j[a] : emb_i[a - B];   // positive pair value
        float pos = __builtin_amdgcn_rcpf(1.0f + fabsf(ra - pv));
        rowv = __logf(denom) - 2.0f * pos;
    }
    // wave shuffle reduce (only waves 0..3 carry nonzero)
    for (int off = 32; off > 0; off >>= 1)
        rowv += __shfl_down(rowv, off, 64);
    if ((t & 63) == 0) red[t >> 6] = rowv;
    __syncthreads();

    if (t == 0) {
        float s = 0.0f;
#pragma unroll
        for (int w = 0; w < 4; ++w) s += red[w];   // waves 4.. wrote 0 anyway
        partials[blockIdx.x] = s;                  // plain store, no atomic
    }
}

__global__ __launch_bounds__(64)
void loss_kernel(const float* __restrict__ partials,
                 float* __restrict__ out, int nparts, int N) {
    float acc = (threadIdx.x < nparts) ? partials[threadIdx.x] : 0.0f;
    for (int off = 32; off > 0; off >>= 1)
        acc += __shfl_down(acc, off, 64);
    if (threadIdx.x == 0) out[0] = acc / (float)N;
}

extern "C" void kernel_launch(void* const* d_in, const int* in_sizes, int n_in,
                              void* d_out, int out_size, void* d_ws, size_t ws_size,
                              hipStream_t stream) {
    const float* emb_i = (const float*)d_in[0];
    const float* emb_j = (const float*)d_in[1];
    const int B = in_sizes[0];
    const int N = 2 * B;
    const int nblocks = N / ROWS_PER_BLOCK;   // 64

    float* partials = (float*)d_ws;           // nblocks floats
    float* out      = (float*)d_out;

    denom_kernel<<<nblocks, KA_THREADS, 0, stream>>>(
        (const float4*)emb_i, (const float4*)emb_j,
        emb_i, emb_j, partials, B);
    loss_kernel<<<1, 64, 0, stream>>>(partials, out, nblocks, N);
}